// Round 4
// baseline (310.035 us; speedup 1.0000x reference)
//
#include <hip/hip_runtime.h>

// weight_noise: out[i] = noise[i] * GAMMA * sqrt(sum_k (2^k * bit_k(w))^2) / 2^WF
// where w = trunc(x[i] * 2^WF), GAMMA=0.05, WF=14.
// sum_k 4^k * bit_k(w) == zero-interleave (spread) of w's bits to even positions.
// Purely elementwise: 12 B/element ideal traffic (402.6 MB/dispatch; ~134 MB of
// reads served below the FETCH counter across dispatches).
//
// R4: MACHINE-CODE-FORCED 16-deep load batch. R1-R3 post-mortem: every
// compiler-hinted batch (unroll arrays, launch_bounds, sched_barrier) was
// serialized by the backend (VGPR stayed 24-40; 16 in-flight f4 loads need
// >=64 payload VGPRs). Here the 16 loads are inline-asm global_load_dwordx4
// (SGPR base + 32-bit voffset, 8 shared voffsets), drained by explicit
// s_waitcnt vmcnt(8)/vmcnt(0), each followed by sched_barrier(0) per guide
// rule #18 (hipcc hoists register-only VALU past inline-asm waitcnt without
// the fence). Decision rule: VGPR>=80 validates the experiment; if dur_us is
// then still ~104-112, per-wave MLP is not the wall -> memory-mix ceiling
// -> ROOFLINE.

typedef float f4 __attribute__((ext_vector_type(4)));

__device__ __forceinline__ float sigma_of(float x) {
    // x in [0,1): trunc toward zero matches jnp astype(int32)
    unsigned w = (unsigned)(int)(x * 16384.0f);      // 14-bit value
    // spread bits: bit k -> bit 2k (handles up to 16 source bits)
    unsigned a = w;
    a = (a | (a << 8)) & 0x00FF00FFu;
    a = (a | (a << 4)) & 0x0F0F0F0Fu;
    a = (a | (a << 2)) & 0x33333333u;
    a = (a | (a << 1)) & 0x55555555u;
    // gamma * sqrt(acc) / 2^14  (power-of-two scale is exact)
    return (0.05f * sqrtf((float)a)) * (1.0f / 16384.0f);
}

__device__ __forceinline__ f4 body(f4 xv, f4 nv) {
    f4 ov;
    ov.x = nv.x * sigma_of(xv.x);
    ov.y = nv.y * sigma_of(xv.y);
    ov.z = nv.z * sigma_of(xv.z);
    ov.w = nv.w * sigma_of(xv.w);
    return ov;
}

#define F4_PER_THREAD 8
#define F4_PER_BLOCK (F4_PER_THREAD * 256)   // 2048 f4 = 32 KB per array

#define GLOAD(dst, voff, sbase) \
    asm volatile("global_load_dwordx4 %0, %1, %2" \
                 : "=v"(dst) : "v"(voff), "s"(sbase))

__global__ __launch_bounds__(256, 4) void weight_noise_kernel(
    const float* __restrict__ xp,
    const float* __restrict__ np_,
    float* __restrict__ op,
    int count4)
{
    const int t = threadIdx.x;
    const unsigned base = (unsigned)blockIdx.x * F4_PER_BLOCK + (unsigned)t;

    if (base + (F4_PER_THREAD - 1) * 256 < (unsigned)count4) {
        // Byte offsets shared by the x and n streams (one VGPR each).
        // Load u touches bytes [u*4096 + t*16, +16) of the block's 32 KB
        // segment: lane-contiguous 1 KB per instruction, sequential stream.
        unsigned off0 = (base + 0 * 256) * 16u;
        unsigned off1 = (base + 1 * 256) * 16u;
        unsigned off2 = (base + 2 * 256) * 16u;
        unsigned off3 = (base + 3 * 256) * 16u;
        unsigned off4 = (base + 4 * 256) * 16u;
        unsigned off5 = (base + 5 * 256) * 16u;
        unsigned off6 = (base + 6 * 256) * 16u;
        unsigned off7 = (base + 7 * 256) * 16u;

        f4 x0, x1, x2, x3, x4v, x5, x6, x7;
        f4 n0, n1, n2, n3, n4v, n5, n6, n7;

        // 16 loads in flight, pairwise (x,n) so vmcnt(8) releases bodies 0-3.
        GLOAD(x0, off0, xp);  GLOAD(n0, off0, np_);
        GLOAD(x1, off1, xp);  GLOAD(n1, off1, np_);
        GLOAD(x2, off2, xp);  GLOAD(n2, off2, np_);
        GLOAD(x3, off3, xp);  GLOAD(n3, off3, np_);
        GLOAD(x4v, off4, xp); GLOAD(n4v, off4, np_);
        GLOAD(x5, off5, xp);  GLOAD(n5, off5, np_);
        GLOAD(x6, off6, xp);  GLOAD(n6, off6, np_);
        GLOAD(x7, off7, xp);  GLOAD(n7, off7, np_);

        asm volatile("s_waitcnt vmcnt(8)" ::: "memory");
        __builtin_amdgcn_sched_barrier(0);   // rule #18: pin VALU below wait
        f4 o0 = body(x0, n0);
        f4 o1 = body(x1, n1);
        f4 o2 = body(x2, n2);
        f4 o3 = body(x3, n3);

        asm volatile("s_waitcnt vmcnt(0)" ::: "memory");
        __builtin_amdgcn_sched_barrier(0);
        f4 o4 = body(x4v, n4v);
        f4 o5 = body(x5, n5);
        f4 o6 = body(x6, n6);
        f4 o7 = body(x7, n7);

        f4* o4p = (f4*)op;
        o4p[base + 0 * 256] = o0;
        o4p[base + 1 * 256] = o1;
        o4p[base + 2 * 256] = o2;
        o4p[base + 3 * 256] = o3;
        o4p[base + 4 * 256] = o4;
        o4p[base + 5 * 256] = o5;
        o4p[base + 6 * 256] = o6;
        o4p[base + 7 * 256] = o7;
    } else {
        // Tail (not taken for the bench shape: 8388608 % 2048 == 0).
        const f4* x4p = (const f4*)xp;
        const f4* n4p = (const f4*)np_;
        f4* o4p = (f4*)op;
        for (unsigned i = base; i < (unsigned)count4; i += 256) {
            o4p[i] = body(x4p[i], n4p[i]);
        }
    }
}

extern "C" void kernel_launch(void* const* d_in, const int* in_sizes, int n_in,
                              void* d_out, int out_size, void* d_ws, size_t ws_size,
                              hipStream_t stream) {
    const float* xp = (const float*)d_in[0];     // x, float32
    const float* nz = (const float*)d_in[1];     // noise_n, float32
    float* out = (float*)d_out;                  // float32 output
    int n = in_sizes[0];                         // 4096*8192 = 33554432
    int count4 = n / 4;                          // 8388608
    int block = 256;
    int grid = (count4 + F4_PER_BLOCK - 1) / F4_PER_BLOCK;   // 4096 blocks
    weight_noise_kernel<<<grid, block, 0, stream>>>(xp, nz, out, count4);
}